// Round 1
// baseline (97.352 us; speedup 1.0000x reference)
//
#include <hip/hip_runtime.h>
#include <math.h>

// InfoNCE loss, B=16 N=4096 D=1024, A = B*N anchors, T = 0.1.
// loss_i = softplus((neg_i - pos_i) / T), output = mean over anchors.
// Memory-bound gather: one 64-lane wave per anchor, float4 loads (1 KB/wave/instr).

#define EMB_D 1024
#define TEMP_INV 10.0f
#define NBLOCKS 2048
#define NTHREADS 256
#define WAVES_PER_BLOCK (NTHREADS / 64)

__global__ __launch_bounds__(NTHREADS) void infonce_partial_kernel(
    const float* __restrict__ emb,
    const int* __restrict__ anchor_idx,
    const int* __restrict__ pos_idx,
    const int* __restrict__ neg_idx,
    float* __restrict__ ws_partial,
    int A)
{
    __shared__ float wave_sums[WAVES_PER_BLOCK];

    const int tid  = threadIdx.x;
    const int lane = tid & 63;
    const int wid  = tid >> 6;
    const int gwave  = blockIdx.x * WAVES_PER_BLOCK + wid;
    const int nwaves = gridDim.x * WAVES_PER_BLOCK;

    float loss_sum = 0.0f;

    for (int a = gwave; a < A; a += nwaves) {
        const float4* ar = (const float4*)(emb + (size_t)anchor_idx[a] * EMB_D);
        const float4* pr = (const float4*)(emb + (size_t)pos_idx[a]    * EMB_D);
        const float4* nr = (const float4*)(emb + (size_t)neg_idx[a]    * EMB_D);

        float dp = 0.0f, dn = 0.0f;
        #pragma unroll
        for (int it = 0; it < EMB_D / 4 / 64; ++it) {
            const int j = lane + it * 64;
            const float4 av = ar[j];
            const float4 pv = pr[j];
            const float4 nv = nr[j];
            dp = fmaf(av.x, pv.x, dp);
            dp = fmaf(av.y, pv.y, dp);
            dp = fmaf(av.z, pv.z, dp);
            dp = fmaf(av.w, pv.w, dp);
            dn = fmaf(av.x, nv.x, dn);
            dn = fmaf(av.y, nv.y, dn);
            dn = fmaf(av.z, nv.z, dn);
            dn = fmaf(av.w, nv.w, dn);
        }

        // Wave-wide butterfly reduce (64 lanes) — all lanes end with the full dot.
        #pragma unroll
        for (int off = 32; off >= 1; off >>= 1) {
            dp += __shfl_xor(dp, off, 64);
            dn += __shfl_xor(dn, off, 64);
        }

        // Numerically stable softplus((neg - pos) * 10)
        const float d = (dn - dp) * TEMP_INV;
        const float loss = (d > 0.0f) ? (d + log1pf(__expf(-d)))
                                      : log1pf(__expf(d));
        loss_sum += loss;  // identical value on all 64 lanes
    }

    if (lane == 0) wave_sums[wid] = loss_sum;
    __syncthreads();

    if (tid == 0) {
        float s = 0.0f;
        #pragma unroll
        for (int i = 0; i < WAVES_PER_BLOCK; ++i) s += wave_sums[i];
        ws_partial[blockIdx.x] = s;
    }
}

__global__ __launch_bounds__(256) void infonce_reduce_kernel(
    const float* __restrict__ ws_partial,
    float* __restrict__ out,
    int nparts,
    float invA)
{
    __shared__ double sh[256];
    double s = 0.0;
    for (int i = threadIdx.x; i < nparts; i += 256) s += (double)ws_partial[i];
    sh[threadIdx.x] = s;
    __syncthreads();
    #pragma unroll
    for (int off = 128; off >= 1; off >>= 1) {
        if (threadIdx.x < off) sh[threadIdx.x] += sh[threadIdx.x + off];
        __syncthreads();
    }
    if (threadIdx.x == 0) out[0] = (float)(sh[0] * (double)invA);
}

extern "C" void kernel_launch(void* const* d_in, const int* in_sizes, int n_in,
                              void* d_out, int out_size, void* d_ws, size_t ws_size,
                              hipStream_t stream) {
    const float* emb        = (const float*)d_in[0];
    const int*   anchor_idx = (const int*)d_in[1];
    const int*   pos_idx    = (const int*)d_in[2];
    const int*   neg_idx    = (const int*)d_in[3];
    const int    A          = in_sizes[1];

    float* ws  = (float*)d_ws;   // NBLOCKS partial sums
    float* out = (float*)d_out;

    infonce_partial_kernel<<<NBLOCKS, NTHREADS, 0, stream>>>(
        emb, anchor_idx, pos_idx, neg_idx, ws, A);
    infonce_reduce_kernel<<<1, 256, 0, stream>>>(
        ws, out, NBLOCKS, 1.0f / (float)A);
}

// Round 2
// 90.645 us; speedup vs baseline: 1.0740x; 1.0740x over previous
//
#include <hip/hip_runtime.h>
#include <math.h>

// InfoNCE loss, B=16 N=4096 D=1024, A = B*N anchors, T = 0.1.
// loss_i = softplus((neg_i - pos_i) / T), output = mean over anchors.
//
// Key structure exploit: reference builds pos = roll(perm, 1) per group, so
// pos_idx[a] == anchor_idx[a-1] for all but the first anchor of each group.
// Each wave processes a CONTIGUOUS chunk of anchors and keeps the previous
// anchor's row in registers (16 floats/lane); when pos_idx[a]==prev anchor idx
// (checked at runtime, wave-uniform) the positive row load is free.
// Cuts logical gather traffic from 3 rows/anchor to ~2 rows/anchor.

#define EMB_D 1024
#define TEMP_INV 10.0f
#define NBLOCKS 2048
#define NTHREADS 256
#define WAVES_PER_BLOCK (NTHREADS / 64)

__device__ __forceinline__ float dot4(const float4 a, const float4 b, float acc) {
    acc = fmaf(a.x, b.x, acc);
    acc = fmaf(a.y, b.y, acc);
    acc = fmaf(a.z, b.z, acc);
    acc = fmaf(a.w, b.w, acc);
    return acc;
}

__global__ __launch_bounds__(NTHREADS) void infonce_partial_kernel(
    const float* __restrict__ emb,
    const int* __restrict__ anchor_idx,
    const int* __restrict__ pos_idx,
    const int* __restrict__ neg_idx,
    float* __restrict__ ws_partial,
    int A)
{
    __shared__ float wave_sums[WAVES_PER_BLOCK];

    const int tid  = threadIdx.x;
    const int lane = tid & 63;
    const int wid  = tid >> 6;
    const int gwave  = blockIdx.x * WAVES_PER_BLOCK + wid;
    const int nwaves = NBLOCKS * WAVES_PER_BLOCK;

    // Contiguous chunk per wave (A = 65536, nwaves = 8192 -> chunk = 8).
    const int chunk = (A + nwaves - 1) / nwaves;
    const int a0 = gwave * chunk;
    const int a1 = (a0 + chunk < A) ? (a0 + chunk) : A;

    float loss_sum = 0.0f;

    int prev_ai = -1;
    float4 pv[4];  // previous anchor's row (candidate positive row)
    pv[0] = pv[1] = pv[2] = pv[3] = make_float4(0.f, 0.f, 0.f, 0.f);

    for (int a = a0; a < a1; ++a) {
        const int ai = anchor_idx[a];
        const int pi = pos_idx[a];
        const int ni = neg_idx[a];

        const float4* ar = (const float4*)(emb + (size_t)ai * EMB_D);
        const float4* nr = (const float4*)(emb + (size_t)ni * EMB_D);

        float4 av[4], nv[4];
        #pragma unroll
        for (int it = 0; it < 4; ++it) {
            av[it] = ar[lane + it * 64];
            nv[it] = nr[lane + it * 64];
        }

        float dp = 0.0f, dn = 0.0f;
        if (pi == prev_ai) {
            // positive row == previous anchor row, already in registers
            #pragma unroll
            for (int it = 0; it < 4; ++it) dp = dot4(av[it], pv[it], dp);
        } else {
            const float4* pr = (const float4*)(emb + (size_t)pi * EMB_D);
            #pragma unroll
            for (int it = 0; it < 4; ++it) {
                const float4 t = pr[lane + it * 64];
                dp = dot4(av[it], t, dp);
            }
        }
        #pragma unroll
        for (int it = 0; it < 4; ++it) dn = dot4(av[it], nv[it], dn);

        // carry anchor row to next iteration (register rename, no copy in asm)
        #pragma unroll
        for (int it = 0; it < 4; ++it) pv[it] = av[it];
        prev_ai = ai;

        // Wave-wide butterfly reduce (64 lanes).
        #pragma unroll
        for (int off = 32; off >= 1; off >>= 1) {
            dp += __shfl_xor(dp, off, 64);
            dn += __shfl_xor(dn, off, 64);
        }

        // Numerically stable softplus((neg - pos) * 10)
        const float d = (dn - dp) * TEMP_INV;
        const float loss = (d > 0.0f) ? (d + log1pf(__expf(-d)))
                                      : log1pf(__expf(d));
        loss_sum += loss;  // identical on all lanes
    }

    if (lane == 0) wave_sums[wid] = loss_sum;
    __syncthreads();

    if (tid == 0) {
        float s = 0.0f;
        #pragma unroll
        for (int i = 0; i < WAVES_PER_BLOCK; ++i) s += wave_sums[i];
        ws_partial[blockIdx.x] = s;
    }
}

__global__ __launch_bounds__(256) void infonce_reduce_kernel(
    const float* __restrict__ ws_partial,
    float* __restrict__ out,
    int nparts,
    float invA)
{
    __shared__ double sh[256];
    double s = 0.0;
    for (int i = threadIdx.x; i < nparts; i += 256) s += (double)ws_partial[i];
    sh[threadIdx.x] = s;
    __syncthreads();
    #pragma unroll
    for (int off = 128; off >= 1; off >>= 1) {
        if (threadIdx.x < off) sh[threadIdx.x] += sh[threadIdx.x + off];
        __syncthreads();
    }
    if (threadIdx.x == 0) out[0] = (float)(sh[0] * (double)invA);
}

extern "C" void kernel_launch(void* const* d_in, const int* in_sizes, int n_in,
                              void* d_out, int out_size, void* d_ws, size_t ws_size,
                              hipStream_t stream) {
    const float* emb        = (const float*)d_in[0];
    const int*   anchor_idx = (const int*)d_in[1];
    const int*   pos_idx    = (const int*)d_in[2];
    const int*   neg_idx    = (const int*)d_in[3];
    const int    A          = in_sizes[1];

    float* ws  = (float*)d_ws;   // NBLOCKS partial sums
    float* out = (float*)d_out;

    infonce_partial_kernel<<<NBLOCKS, NTHREADS, 0, stream>>>(
        emb, anchor_idx, pos_idx, neg_idx, ws, A);
    infonce_reduce_kernel<<<1, 256, 0, stream>>>(
        ws, out, NBLOCKS, 1.0f / (float)A);
}

// Round 3
// 86.947 us; speedup vs baseline: 1.1197x; 1.0425x over previous
//
#include <hip/hip_runtime.h>
#include <math.h>

// InfoNCE loss, B=16 N=4096 D=1024, A = B*N anchors, T = 0.1.
// loss_i = softplus((neg_i - pos_i) / T), output = mean over anchors.
//
// Structure exploit: pos_idx[a] == anchor_idx[a-1] except at group starts,
// so a wave walking a CONTIGUOUS anchor chunk keeps the previous anchor row
// in registers and gets the positive row for free. Traffic is then
//   table-once (anchors, 268 MB) + negs (268 MB) + chunk-boundary pos loads.
// Round 2 measured exactly the BW roofline for that volume (90.6 us).
// This round: chunk 8 -> 16 (4096 waves) halves boundary pos loads
// (33.5 MB -> 16.8 MB), the only remaining reducible traffic.

#define EMB_D 1024
#define TEMP_INV 10.0f
#define NBLOCKS 1024
#define NTHREADS 256
#define WAVES_PER_BLOCK (NTHREADS / 64)
#define NWAVES (NBLOCKS * WAVES_PER_BLOCK)

__device__ __forceinline__ float dot4(const float4 a, const float4 b, float acc) {
    acc = fmaf(a.x, b.x, acc);
    acc = fmaf(a.y, b.y, acc);
    acc = fmaf(a.z, b.z, acc);
    acc = fmaf(a.w, b.w, acc);
    return acc;
}

__global__ __launch_bounds__(NTHREADS) void infonce_partial_kernel(
    const float* __restrict__ emb,
    const int* __restrict__ anchor_idx,
    const int* __restrict__ pos_idx,
    const int* __restrict__ neg_idx,
    float* __restrict__ ws_partial,
    int A)
{
    __shared__ float wave_sums[WAVES_PER_BLOCK];

    const int tid  = threadIdx.x;
    const int lane = tid & 63;
    const int wid  = tid >> 6;
    const int gwave = blockIdx.x * WAVES_PER_BLOCK + wid;

    // Contiguous chunk per wave (A = 65536, NWAVES = 4096 -> chunk = 16).
    const int chunk = (A + NWAVES - 1) / NWAVES;
    const int a0 = gwave * chunk;
    const int a1 = (a0 + chunk < A) ? (a0 + chunk) : A;

    float loss_sum = 0.0f;

    int prev_ai = -1;
    float4 pv[4];  // previous anchor's row (candidate positive row)
    pv[0] = pv[1] = pv[2] = pv[3] = make_float4(0.f, 0.f, 0.f, 0.f);

    for (int a = a0; a < a1; ++a) {
        const int ai = anchor_idx[a];
        const int pi = pos_idx[a];
        const int ni = neg_idx[a];

        const float4* ar = (const float4*)(emb + (size_t)ai * EMB_D);
        const float4* nr = (const float4*)(emb + (size_t)ni * EMB_D);

        float4 av[4], nv[4];
        #pragma unroll
        for (int it = 0; it < 4; ++it) {
            av[it] = ar[lane + it * 64];
            nv[it] = nr[lane + it * 64];
        }

        float dp = 0.0f, dn = 0.0f;
        if (pi == prev_ai) {
            // positive row == previous anchor row, already in registers
            #pragma unroll
            for (int it = 0; it < 4; ++it) dp = dot4(av[it], pv[it], dp);
        } else {
            const float4* pr = (const float4*)(emb + (size_t)pi * EMB_D);
            #pragma unroll
            for (int it = 0; it < 4; ++it) {
                const float4 t = pr[lane + it * 64];
                dp = dot4(av[it], t, dp);
            }
        }
        #pragma unroll
        for (int it = 0; it < 4; ++it) dn = dot4(av[it], nv[it], dn);

        // carry anchor row to next iteration
        #pragma unroll
        for (int it = 0; it < 4; ++it) pv[it] = av[it];
        prev_ai = ai;

        // Wave-wide butterfly reduce (64 lanes).
        #pragma unroll
        for (int off = 32; off >= 1; off >>= 1) {
            dp += __shfl_xor(dp, off, 64);
            dn += __shfl_xor(dn, off, 64);
        }

        // Numerically stable softplus((neg - pos) * 10)
        const float d = (dn - dp) * TEMP_INV;
        const float loss = (d > 0.0f) ? (d + log1pf(__expf(-d)))
                                      : log1pf(__expf(d));
        loss_sum += loss;  // identical on all lanes
    }

    if (lane == 0) wave_sums[wid] = loss_sum;
    __syncthreads();

    if (tid == 0) {
        float s = 0.0f;
        #pragma unroll
        for (int i = 0; i < WAVES_PER_BLOCK; ++i) s += wave_sums[i];
        ws_partial[blockIdx.x] = s;
    }
}

__global__ __launch_bounds__(256) void infonce_reduce_kernel(
    const float* __restrict__ ws_partial,
    float* __restrict__ out,
    int nparts,
    float invA)
{
    __shared__ double sh[256];
    double s = 0.0;
    for (int i = threadIdx.x; i < nparts; i += 256) s += (double)ws_partial[i];
    sh[threadIdx.x] = s;
    __syncthreads();
    #pragma unroll
    for (int off = 128; off >= 1; off >>= 1) {
        if (threadIdx.x < off) sh[threadIdx.x] += sh[threadIdx.x + off];
        __syncthreads();
    }
    if (threadIdx.x == 0) out[0] = (float)(sh[0] * (double)invA);
}

extern "C" void kernel_launch(void* const* d_in, const int* in_sizes, int n_in,
                              void* d_out, int out_size, void* d_ws, size_t ws_size,
                              hipStream_t stream) {
    const float* emb        = (const float*)d_in[0];
    const int*   anchor_idx = (const int*)d_in[1];
    const int*   pos_idx    = (const int*)d_in[2];
    const int*   neg_idx    = (const int*)d_in[3];
    const int    A          = in_sizes[1];

    float* ws  = (float*)d_ws;   // NBLOCKS partial sums
    float* out = (float*)d_out;

    infonce_partial_kernel<<<NBLOCKS, NTHREADS, 0, stream>>>(
        emb, anchor_idx, pos_idx, neg_idx, ws, A);
    infonce_reduce_kernel<<<1, 256, 0, stream>>>(
        ws, out, NBLOCKS, 1.0f / (float)A);
}